// Round 1
// baseline (271.914 us; speedup 1.0000x reference)
//
#include <hip/hip_runtime.h>
#include <hip/hip_bf16.h>
#include <math.h>

// ---------------------------------------------------------------------------
// ClusteringModule: e = (z@W1+b1)@W2+b2 ; s = rownorm(1/(1+||e-c||)) ; c=argmax
// Round 4: GEMM1 restructured to 128x256 block tile, 8 waves x (64x64),
// counted-vmcnt double-buffer pipeline (raw s_barrier + s_waitcnt vmcnt(6))
// so staging loads span the barrier. 96 KiB dynamic LDS, 1 block/CU.
// split_z / split_w / head_kernel unchanged (numerics identical).
// ---------------------------------------------------------------------------

typedef __bf16 bf16x8 __attribute__((ext_vector_type(8)));
typedef float  f32x4  __attribute__((ext_vector_type(4)));
typedef unsigned short ushort8 __attribute__((ext_vector_type(8)));

#define MROWS 2048
#define KDIM  12000
#define N1    1024
#define N2    64
#define NCL   100

constexpr int KT = 375;          // k-tiles of 32
constexpr int MT = 16;           // m-tiles of 128
constexpr int NT = 8;            // n-tiles of 128 (split_w layout unchanged)
constexpr int TILE_E = 4096;     // 128x32 bf16 elems per tile (8192 B)
constexpr long long AE = (long long)MT * KT * TILE_E;
constexpr long long BE = (long long)NT * KT * TILE_E;

__device__ __forceinline__ unsigned short f2bf(float f) {
  unsigned int u = __float_as_uint(f);
  return (unsigned short)((u + 0x7FFFu + ((u >> 16) & 1u)) >> 16);   // RNE
}
__device__ __forceinline__ float bf2f(unsigned short h) {
  return __uint_as_float(((unsigned int)h) << 16);
}

__device__ __forceinline__ void gl_lds16(const unsigned short* g, unsigned short* l) {
  __builtin_amdgcn_global_load_lds((const __attribute__((address_space(1))) void*)g,
                                   (__attribute__((address_space(3))) void*)l, 16, 0, 0);
}

// ------------------- pre-split: z -> Ah/Al (transpose-free) -----------------
__global__ __launch_bounds__(256) void split_z(const float* __restrict__ z,
                                               unsigned short* __restrict__ Ah,
                                               unsigned short* __restrict__ Al) {
  const int t  = threadIdx.x;
  const int kt = blockIdx.x, mt = blockIdx.y;
  const long long tb = (long long)(mt * KT + kt) * TILE_E;
#pragma unroll
  for (int i = 0; i < 2; ++i) {
    const int idx = i * 256 + t;           // 0..511
    const int r   = idx >> 2;              // 0..127
    const int k16 = idx & 3;               // 0..3
    const float* src = z + (long long)(mt * 128 + r) * KDIM + kt * 32 + k16 * 8;
    const float4 v0 = *(const float4*)src;
    const float4 v1 = *(const float4*)(src + 4);
    const float vv[8] = {v0.x, v0.y, v0.z, v0.w, v1.x, v1.y, v1.z, v1.w};
    ushort8 h, l;
#pragma unroll
    for (int j = 0; j < 8; ++j) {
      const unsigned short hs = f2bf(vv[j]);
      h[j] = hs; l[j] = f2bf(vv[j] - bf2f(hs));
    }
    const long long o = tb + (long long)(k16 * 128 + r) * 8;
    *(ushort8*)&Ah[o] = h;
    *(ushort8*)&Al[o] = l;
  }
}

// --------------------- pre-split: W1 -> Bh/Bl (transposed) ------------------
__global__ __launch_bounds__(256) void split_w(const float* __restrict__ W1,
                                               unsigned short* __restrict__ Bh,
                                               unsigned short* __restrict__ Bl) {
  __shared__ float tile[32][129];
  const int t = threadIdx.x;
  const int kt = blockIdx.x, nt = blockIdx.y;
  const float* src = W1 + (long long)(kt * 32) * N1 + nt * 128;
#pragma unroll
  for (int i = 0; i < 4; ++i) {
    const int idx = i * 256 + t, r = idx >> 5, c4 = idx & 31;
    const float4 v = *(const float4*)(src + (long long)r * N1 + c4 * 4);
    tile[r][c4 * 4 + 0] = v.x; tile[r][c4 * 4 + 1] = v.y;
    tile[r][c4 * 4 + 2] = v.z; tile[r][c4 * 4 + 3] = v.w;
  }
  __syncthreads();
  const long long tb = (long long)(nt * KT + kt) * TILE_E;
#pragma unroll
  for (int i = 0; i < 2; ++i) {
    const int q = i * 256 + t, k16 = q >> 7, col = q & 127;
    ushort8 h, l;
#pragma unroll
    for (int j = 0; j < 8; ++j) {
      const float f = tile[k16 * 8 + j][col];
      const unsigned short hs = f2bf(f);
      h[j] = hs; l[j] = f2bf(f - bf2f(hs));
    }
    *(ushort8*)&Bh[tb + q * 8] = h;
    *(ushort8*)&Bl[tb + q * 8] = l;
  }
}

// ----------------------- GEMM1: split-3 bf16 MFMA ---------------------------
// 128x256 tile, BK=32, 8 waves x (64x64), K-split-4 -> 256 blocks of 512 thr.
// Dynamic LDS 96 KiB (2 x {Ah 8K, Al 8K, Bh 16K, Bl 16K}); 1 block/CU.
// Counted-vmcnt pipeline: 6 global_load_lds per stage; s_waitcnt vmcnt(6)
// waits only the PREVIOUS stage's loads, so the current prefetch spans the
// barrier with a full K-step of slack.
constexpr int BUF_SH = 24576;    // shorts per buffer (48 KiB)

__global__ __launch_bounds__(512, 2)
void gemm_split3(const unsigned short* __restrict__ Ah, const unsigned short* __restrict__ Al,
                 const unsigned short* __restrict__ Bh, const unsigned short* __restrict__ Bl,
                 const float* __restrict__ b1, float* __restrict__ e1p)
{
  extern __shared__ unsigned short lds[];   // 2 * 24576 shorts = 96 KiB
  const int t = threadIdx.x, lane = t & 63, w = t >> 6;   // w: 0..7
  const int wr = w >> 2, wc = w & 3;                      // wave tile: 64x64
  const int bid = blockIdx.x;
  const int wg = ((bid & 7) << 5) | (bid >> 3);  // XCD chunked swizzle, 256%8==0
  const int ks  = wg >> 6;                       // 0..3
  const int mt  = (wg >> 2) & 15;                // 0..15
  const int nt2 = wg & 3;                        // 0..3 (256-wide n-tile)
  const int s0 = ks * 94;
  const int nst = (ks == 3) ? 93 : 94;

  const unsigned short* ga0  = Ah + (long long)(mt * KT + s0) * TILE_E;
  const unsigned short* ga1  = Al + (long long)(mt * KT + s0) * TILE_E;
  const unsigned short* gb0h = Bh + (long long)((2 * nt2)     * KT + s0) * TILE_E;
  const unsigned short* gb1h = Bh + (long long)((2 * nt2 + 1) * KT + s0) * TILE_E;
  const unsigned short* gb0l = Bl + (long long)((2 * nt2)     * KT + s0) * TILE_E;
  const unsigned short* gb1l = Bl + (long long)((2 * nt2 + 1) * KT + s0) * TILE_E;

  // LDS per buffer (shorts): Ah[0,4096) Al[4096,8192) Bh[8192,16384) Bl[16384,24576)
  auto stage = [&](int buf, int s) {   // 6 x (512 thr x 16B = 8KB)
    const long long so = (long long)s * TILE_E + t * 8;
    unsigned short* L = lds + buf * BUF_SH;
    gl_lds16(ga0  + so, L +             t * 8);
    gl_lds16(ga1  + so, L +  4096     + t * 8);
    gl_lds16(gb0h + so, L +  8192     + t * 8);
    gl_lds16(gb1h + so, L +  8192 + 4096 + t * 8);
    gl_lds16(gb0l + so, L + 16384     + t * 8);
    gl_lds16(gb1l + so, L + 16384 + 4096 + t * 8);
  };

  f32x4 acc[4][4] = {};

  auto compute = [&](int buf) {
    const int fr = lane & 15, k16 = lane >> 4;
    const unsigned short* L = lds + buf * BUF_SH;
    bf16x8 ah[4], al[4], bh[4], bl[4];
#pragma unroll
    for (int mf = 0; mf < 4; ++mf) {
      const int row = wr * 64 + mf * 16 + fr;
      ah[mf] = *(const bf16x8*)(L +        k16 * 1024 + row * 8);
      al[mf] = *(const bf16x8*)(L + 4096 + k16 * 1024 + row * 8);
    }
#pragma unroll
    for (int nf = 0; nf < 4; ++nf) {
      const int col = wc * 64 + nf * 16 + fr;     // 0..255
      const int sub = col >> 7, c = col & 127;
      bh[nf] = *(const bf16x8*)(L +  8192 + sub * 4096 + k16 * 1024 + c * 8);
      bl[nf] = *(const bf16x8*)(L + 16384 + sub * 4096 + k16 * 1024 + c * 8);
    }
    __builtin_amdgcn_s_setprio(1);
#pragma unroll
    for (int mf = 0; mf < 4; ++mf)
#pragma unroll
      for (int nf = 0; nf < 4; ++nf)
        acc[mf][nf] = __builtin_amdgcn_mfma_f32_16x16x32_bf16(ah[mf], bh[nf], acc[mf][nf], 0, 0, 0);
#pragma unroll
    for (int mf = 0; mf < 4; ++mf)
#pragma unroll
      for (int nf = 0; nf < 4; ++nf)
        acc[mf][nf] = __builtin_amdgcn_mfma_f32_16x16x32_bf16(ah[mf], bl[nf], acc[mf][nf], 0, 0, 0);
#pragma unroll
    for (int mf = 0; mf < 4; ++mf)
#pragma unroll
      for (int nf = 0; nf < 4; ++nf)
        acc[mf][nf] = __builtin_amdgcn_mfma_f32_16x16x32_bf16(al[mf], bh[nf], acc[mf][nf], 0, 0, 0);
    __builtin_amdgcn_s_setprio(0);
  };

  stage(0, 0);
  int buf = 0;
  for (int s = 0; s < nst - 1; ++s) {
    stage(buf ^ 1, s + 1);                          // 6 loads for next tile
    asm volatile("s_waitcnt vmcnt(6)" ::: "memory"); // prev 6 (this tile) done
    __builtin_amdgcn_s_barrier();                   // all waves: tile ready
    __builtin_amdgcn_sched_barrier(0);
    compute(buf);
    __builtin_amdgcn_s_barrier();                   // all reads done before overwrite
    __builtin_amdgcn_sched_barrier(0);
    buf ^= 1;
  }
  asm volatile("s_waitcnt vmcnt(0)" ::: "memory");  // last tile's loads done
  __builtin_amdgcn_s_barrier();
  __builtin_amdgcn_sched_barrier(0);
  compute(buf);

  // Epilogue: C/D layout col=lane&15, row=(lane>>4)*4+reg (verified mapping)
  float* eo = e1p + (long long)ks * MROWS * N1;
#pragma unroll
  for (int mf = 0; mf < 4; ++mf) {
    const int r0 = mt * 128 + wr * 64 + mf * 16 + ((lane >> 4) << 2);
#pragma unroll
    for (int nf = 0; nf < 4; ++nf) {
      const int col = nt2 * 256 + wc * 64 + nf * 16 + (lane & 15);
      const float bias = (ks == 0) ? b1[col] : 0.0f;
#pragma unroll
      for (int r = 0; r < 4; ++r)
        eo[(long long)(r0 + r) * N1 + col] = acc[mf][nf][r] + bias;
    }
  }
}

// ------------------------ GEMM2 + distances + argmax ------------------------
constexpr int RPB = 8;

__global__ __launch_bounds__(256, 2)
void head_kernel(const float* __restrict__ e1, const float* __restrict__ W2,
                 const float* __restrict__ b2, const float* __restrict__ cents,
                 float* __restrict__ eOut, float* __restrict__ sOut,
                 float* __restrict__ cOut)
{
  __shared__ float cent_s[NCL * 65];
  __shared__ float e_s[RPB][N2 + 4];
  const int t = threadIdx.x;
  const int r0 = blockIdx.x * RPB;
  constexpr long long PS = (long long)MROWS * N1;

  for (int i = t; i < NCL * N2; i += 256) {
    const int c = i >> 6, d = i & 63;
    cent_s[c * 65 + d] = cents[i];
  }

  const int n = t & 63;
  const int rq = t >> 6;
  float acc0 = 0.f, acc1 = 0.f;
  const float* e1r0 = e1 + (long long)(r0 + rq) * N1;
  const float* e1r1 = e1 + (long long)(r0 + rq + 4) * N1;
  for (int k = 0; k < N1; k += 4) {
    f32x4 x0 = *(const f32x4*)(e1r0 + k);
    f32x4 x1 = *(const f32x4*)(e1r1 + k);
#pragma unroll
    for (int p = 1; p < 4; ++p) {
      x0 += *(const f32x4*)(e1r0 + p * PS + k);
      x1 += *(const f32x4*)(e1r1 + p * PS + k);
    }
    const float w0 = W2[(k + 0) * N2 + n];
    const float w1 = W2[(k + 1) * N2 + n];
    const float w2 = W2[(k + 2) * N2 + n];
    const float w3 = W2[(k + 3) * N2 + n];
    acc0 = fmaf(x0[0], w0, acc0); acc0 = fmaf(x0[1], w1, acc0);
    acc0 = fmaf(x0[2], w2, acc0); acc0 = fmaf(x0[3], w3, acc0);
    acc1 = fmaf(x1[0], w0, acc1); acc1 = fmaf(x1[1], w1, acc1);
    acc1 = fmaf(x1[2], w2, acc1); acc1 = fmaf(x1[3], w3, acc1);
  }
  acc0 += b2[n]; acc1 += b2[n];
  eOut[(long long)(r0 + rq) * N2 + n]     = acc0;
  eOut[(long long)(r0 + rq + 4) * N2 + n] = acc1;
  e_s[rq][n]     = acc0;
  e_s[rq + 4][n] = acc1;
  __syncthreads();

  const int row = t >> 5;
  const int ci  = t & 31;
  float sum = 0.f, bestv = -1.f;
  int bestc = 0;
  float sv[4] = {0.f, 0.f, 0.f, 0.f};
#pragma unroll
  for (int j = 0; j < 4; ++j) {
    const int c = ci + 32 * j;
    if (c < NCL) {
      float d2 = 0.f;
#pragma unroll 8
      for (int d = 0; d < N2; ++d) {
        const float diff = e_s[row][d] - cent_s[c * 65 + d];
        d2 = fmaf(diff, diff, d2);
      }
      const float su = 1.0f / (1.0f + sqrtf(d2));
      sv[j] = su; sum += su;
      if (su > bestv) { bestv = su; bestc = c; }
    }
  }
#pragma unroll
  for (int off = 1; off < 32; off <<= 1) {
    sum += __shfl_xor(sum, off);
    const float ov = __shfl_xor(bestv, off);
    const int   oc = __shfl_xor(bestc, off);
    if (ov > bestv || (ov == bestv && oc < bestc)) { bestv = ov; bestc = oc; }
  }
  const float inv = 1.0f / sum;
#pragma unroll
  for (int j = 0; j < 4; ++j) {
    const int c = ci + 32 * j;
    if (c < NCL) sOut[(long long)(r0 + row) * NCL + c] = sv[j] * inv;
  }
  if (ci == 0) cOut[r0 + row] = (float)bestc;
}

// --------------------------------- launch -----------------------------------
extern "C" void kernel_launch(void* const* d_in, const int* in_sizes, int n_in,
                              void* d_out, int out_size, void* d_ws, size_t ws_size,
                              hipStream_t stream)
{
  const float* z     = (const float*)d_in[0];
  const float* W1    = (const float*)d_in[1];
  const float* b1    = (const float*)d_in[2];
  const float* W2    = (const float*)d_in[3];
  const float* b2    = (const float*)d_in[4];
  const float* cents = (const float*)d_in[5];
  float* out  = (float*)d_out;
  float* eOut = out;
  float* sOut = out + MROWS * N2;
  float* cOut = out + MROWS * N2 + MROWS * NCL;

  unsigned short* Ah = (unsigned short*)d_ws;
  unsigned short* Al = Ah + AE;
  unsigned short* Bh = Al + AE;
  unsigned short* Bl = Bh + BE;
  float* e1p = (float*)(Bl + BE);

  static int lds_set = 0;
  if (!lds_set) {
    hipFuncSetAttribute(reinterpret_cast<const void*>(&gemm_split3),
                        hipFuncAttributeMaxDynamicSharedMemorySize, 2 * BUF_SH * 2);
    lds_set = 1;
  }

  split_z<<<dim3(KT, MT), 256, 0, stream>>>(z, Ah, Al);
  split_w<<<dim3(KT, NT), 256, 0, stream>>>(W1, Bh, Bl);
  gemm_split3<<<256, 512, 2 * BUF_SH * 2, stream>>>(Ah, Al, Bh, Bl, b1, e1p);
  head_kernel<<<MROWS / RPB, 256, 0, stream>>>(e1p, W2, b2, cents, eOut, sOut, cOut);
}